// Round 7
// baseline (3323.971 us; speedup 1.0000x reference)
//
#include <hip/hip_runtime.h>

// ---------------------------------------------------------------------------
// Sparse UNet forward — round 7: rulebook (compacted pair-list) sparse conv.
//   Center tap  -> dense identity GEMM, plain writes (initializes output).
//   Sparse taps -> compacted (out,in) pair tiles, MFMA, atomicAdd scatter.
//   Deconv      -> rulebook segmented by up_k, direct writes (1 write/row).
//   Down        -> rulebook (exactly N pairs), atomicAdd into zeroed buffer.
// ---------------------------------------------------------------------------

#define EPS 1e-4f

typedef __attribute__((ext_vector_type(8))) short short8;   // 8 x bf16
typedef __attribute__((ext_vector_type(4))) float f32x4;

__device__ __forceinline__ unsigned short f2bf(float f) {
    union { float f; unsigned int u; } v; v.f = f;
    unsigned int r = v.u + 0x7fffu + ((v.u >> 16) & 1u);   // RNE
    return (unsigned short)(r >> 16);
}

__global__ void zero_kernel(float* p, long n) {
    long i = (long)blockIdx.x * 256 + threadIdx.x;
    if (i < n) p[i] = 0.f;
}

// Per-channel sum / sumsq -> stats[0:C], stats[C:2C] (atomic accumulate).
template <int C>
__global__ __launch_bounds__(256) void bn_stats(const float* __restrict__ x,
                                                int rows, int stride,
                                                float* __restrict__ stats) {
    const int tid = threadIdx.x;
    const int c = tid & (C - 1);
    const int g = tid / C;
    const int GR = 256 / C;
    float s = 0.f, s2 = 0.f;
    for (int r = blockIdx.x * GR + g; r < rows; r += gridDim.x * GR) {
        float v = x[(size_t)r * stride + c];
        s += v; s2 += v * v;
    }
    __shared__ float sh[2][256];
    sh[0][tid] = s; sh[1][tid] = s2;
    __syncthreads();
    for (int off = 128; off >= C; off >>= 1) {
        if (tid < off) { sh[0][tid] += sh[0][tid + off]; sh[1][tid] += sh[1][tid + off]; }
        __syncthreads();
    }
    if (tid < C) {
        atomicAdd(&stats[c], sh[0][tid]);
        atomicAdd(&stats[C + c], sh[1][tid]);
    }
}

// BN finalize + ReLU -> bf16. Output packed (rows+1) x C, sentinel row zeroed.
template <int C, int CSPLIT>
__global__ __launch_bounds__(256) void bn_norm_relu_bf16(
    const float* __restrict__ x, int rows, int stride,
    const float* __restrict__ stA, const float* __restrict__ stB,
    const float* __restrict__ gamma, const float* __restrict__ beta,
    unsigned short* __restrict__ y) {
    constexpr int TPR = C / 8;
    int gid = blockIdx.x * 256 + threadIdx.x;
    int r = gid / TPR, t = gid % TPR;
    if (r > rows) return;
    short8 o8;
    if (r == rows) {
        for (int j = 0; j < 8; ++j) o8[j] = 0;
    } else {
        const float inv_n = 1.0f / (float)rows;
        const float* xr = x + (size_t)r * stride + t * 8;
        float4 v0 = *(const float4*)(xr);
        float4 v1 = *(const float4*)(xr + 4);
        float vv[8] = {v0.x, v0.y, v0.z, v0.w, v1.x, v1.y, v1.z, v1.w};
#pragma unroll
        for (int j = 0; j < 8; ++j) {
            int c = t * 8 + j;
            const float* st = (c < CSPLIT) ? stA : stB;
            int cc = (c < CSPLIT) ? c : c - CSPLIT;
            int cs = (c < CSPLIT) ? CSPLIT : (C - CSPLIT);
            float mu = st[cc] * inv_n;
            float var = st[cs + cc] * inv_n - mu * mu;
            float sc = gamma[c] * rsqrtf(var + EPS);
            float shf = beta[c] - mu * sc;
            float ov = fmaxf(0.f, fmaf(vv[j], sc, shf));
            o8[j] = (short)f2bf(ov);
        }
    }
    *(short8*)(y + (size_t)r * C + t * 8) = o8;
}

// W [K][CIN][COUT] f32 -> WT [K][COUT][CIN] bf16.
template <int CIN, int COUT>
__global__ void wt_transpose(const float* __restrict__ W, unsigned short* __restrict__ WT, int K) {
    int id = blockIdx.x * 256 + threadIdx.x;
    int total = K * CIN * COUT;
    if (id >= total) return;
    int t = id / (CIN * COUT);
    int r = id % (CIN * COUT);
    int co = r / CIN;
    int ci = r % CIN;
    WT[id] = f2bf(W[(size_t)t * CIN * COUT + ci * COUT + co]);
}

// Rulebook build, 27-tap nets (center tap 13 excluded): for each non-center
// tap kk (compact index), append (m, nbr[k][m]) when valid.
__global__ void build_rb27(const int* __restrict__ nbr, int rows, int P,
                           int cap, int2* __restrict__ rb, int* __restrict__ cnt) {
    int m = blockIdx.x * 256 + threadIdx.x;
    if (m >= rows) return;
    for (int kk = 0; kk < 26; ++kk) {
        int k = kk + (kk >= 13 ? 1 : 0);
        int v = nbr[(size_t)k * rows + m];
        if (v != P) {
            int j = atomicAdd(&cnt[kk], 1);
            if (j < cap) rb[(size_t)kk * cap + j] = make_int2(m, v);
        }
    }
}

// Rulebook build, 8-tap (down conv): all taps sparse-listed.
__global__ void build_rb8(const int* __restrict__ nbr, int rows, int P,
                          int cap, int2* __restrict__ rb, int* __restrict__ cnt) {
    int m = blockIdx.x * 256 + threadIdx.x;
    if (m >= rows) return;
    for (int k = 0; k < 8; ++k) {
        int v = nbr[(size_t)k * rows + m];
        if (v != P) {
            int j = atomicAdd(&cnt[k], 1);
            if (j < cap) rb[(size_t)k * cap + j] = make_int2(m, v);
        }
    }
}

// Rulebook build, deconv: segment fine rows by up_k (each row in exactly one).
__global__ void build_rb_up(const int* __restrict__ up_cidx,
                            const int* __restrict__ up_k,
                            int rows, int cap, int2* __restrict__ rb,
                            int* __restrict__ cnt) {
    int i = blockIdx.x * 256 + threadIdx.x;
    if (i >= rows) return;
    int seg = up_k[i];
    int j = atomicAdd(&cnt[seg], 1);
    if (j < cap) rb[(size_t)seg * cap + j] = make_int2(i, up_cidx[i]);
}

// Dense center-tap GEMM (identity gather): out[m] = fpad[m] @ Wk, plain write.
// Initializes the output buffer for subsequent sparse-tap atomics.
template <int CIN, int COT>
__global__ __launch_bounds__(256) void conv_center(
    const unsigned short* __restrict__ fpad,
    const unsigned short* __restrict__ Wk,     // [COT][CIN] bf16 (tap 13 slice)
    float* __restrict__ out, int rows, int P, int out_stride) {
    constexpr int N_SUB = COT / 16;
    constexpr int K_SUB = CIN / 32;
    const int tid = threadIdx.x;
    const int wave = tid >> 6;
    const int lane = tid & 63;
    const int q = lane >> 4;
    const int l15 = lane & 15;
    const int m0 = blockIdx.x * 128 + wave * 32;

    f32x4 acc[2][N_SUB];
#pragma unroll
    for (int mt = 0; mt < 2; ++mt)
#pragma unroll
        for (int nt = 0; nt < N_SUB; ++nt) acc[mt][nt] = (f32x4){0.f, 0.f, 0.f, 0.f};

    short8 a[2][K_SUB], b[N_SUB][K_SUB];
#pragma unroll
    for (int mt = 0; mt < 2; ++mt) {
        int m = m0 + mt * 16 + l15;
        int src = (m < rows) ? m : P;
#pragma unroll
        for (int kf = 0; kf < K_SUB; ++kf)
            a[mt][kf] = *(const short8*)(fpad + (size_t)src * CIN + kf * 32 + q * 8);
    }
#pragma unroll
    for (int nt = 0; nt < N_SUB; ++nt)
#pragma unroll
        for (int kf = 0; kf < K_SUB; ++kf)
            b[nt][kf] = *(const short8*)(Wk + (size_t)(nt * 16 + l15) * CIN + kf * 32 + q * 8);
#pragma unroll
    for (int mt = 0; mt < 2; ++mt)
#pragma unroll
        for (int nt = 0; nt < N_SUB; ++nt)
#pragma unroll
            for (int kf = 0; kf < K_SUB; ++kf)
                acc[mt][nt] = __builtin_amdgcn_mfma_f32_16x16x32_bf16(
                    a[mt][kf], b[nt][kf], acc[mt][nt], 0, 0, 0);
#pragma unroll
    for (int mt = 0; mt < 2; ++mt)
#pragma unroll
        for (int i = 0; i < 4; ++i) {
            int row = m0 + mt * 16 + q * 4 + i;
            if (row < rows) {
#pragma unroll
                for (int nt = 0; nt < N_SUB; ++nt)
                    out[(size_t)row * out_stride + nt * 16 + l15] = acc[mt][nt][i];
            }
        }
}

// Sparse-tap gather-GEMM over compacted rulebook tiles.
//   grid.y = compact tap; k = tap + (tap>=KSKIP); rb segment [tap*cap .. ).
//   128 entries per block (32/wave). ATOMIC: atomicAdd scatter (overlapping
//   out rows across taps); else plain store (rows unique, deconv).
template <int CIN, int COT, bool ATOMIC>
__global__ __launch_bounds__(256) void conv_sparse(
    const unsigned short* __restrict__ fpad,
    const int2* __restrict__ rb,
    const int* __restrict__ cnt,
    const unsigned short* __restrict__ WT,
    float* __restrict__ out,
    int cap, int kskip, int P, int out_stride) {
    constexpr int N_SUB = COT / 16;
    constexpr int K_SUB = CIN / 32;
    const int tap = blockIdx.y;
    int n = cnt[tap];
    n = n < cap ? n : cap;
    const int base0 = blockIdx.x * 128;
    if (base0 >= n) return;
    const int k = tap + (tap >= kskip ? 1 : 0);
    const int tid = threadIdx.x;
    const int wave = tid >> 6;
    const int lane = tid & 63;
    const int q = lane >> 4;
    const int l15 = lane & 15;
    const int base = base0 + wave * 32;
    const int2* seg = rb + (size_t)tap * cap;

    f32x4 acc[2][N_SUB];
#pragma unroll
    for (int mt = 0; mt < 2; ++mt)
#pragma unroll
        for (int nt = 0; nt < N_SUB; ++nt) acc[mt][nt] = (f32x4){0.f, 0.f, 0.f, 0.f};

    short8 a[2][K_SUB], b[N_SUB][K_SUB];
#pragma unroll
    for (int mt = 0; mt < 2; ++mt) {
        int j = base + mt * 16 + l15;
        int src = (j < n) ? seg[j].y : P;
#pragma unroll
        for (int kf = 0; kf < K_SUB; ++kf)
            a[mt][kf] = *(const short8*)(fpad + (size_t)src * CIN + kf * 32 + q * 8);
    }
    const unsigned short* Wk = WT + (size_t)k * COT * CIN;
#pragma unroll
    for (int nt = 0; nt < N_SUB; ++nt)
#pragma unroll
        for (int kf = 0; kf < K_SUB; ++kf)
            b[nt][kf] = *(const short8*)(Wk + (size_t)(nt * 16 + l15) * CIN + kf * 32 + q * 8);
#pragma unroll
    for (int mt = 0; mt < 2; ++mt)
#pragma unroll
        for (int nt = 0; nt < N_SUB; ++nt)
#pragma unroll
            for (int kf = 0; kf < K_SUB; ++kf)
                acc[mt][nt] = __builtin_amdgcn_mfma_f32_16x16x32_bf16(
                    a[mt][kf], b[nt][kf], acc[mt][nt], 0, 0, 0);

    // C/D layout: col = l15, row-in-subtile = q*4 + i.
#pragma unroll
    for (int mt = 0; mt < 2; ++mt)
#pragma unroll
        for (int i = 0; i < 4; ++i) {
            int j = base + mt * 16 + q * 4 + i;
            if (j < n) {
                int row = seg[j].x;   // broadcast across the 16 l15 lanes
                float* o = out + (size_t)row * out_stride + l15;
#pragma unroll
                for (int nt = 0; nt < N_SUB; ++nt) {
                    if (ATOMIC) atomicAdd(o + nt * 16, acc[mt][nt][i]);
                    else        o[nt * 16] = acc[mt][nt][i];
                }
            }
        }
}

static inline int ceil_div(long a, long b) { return (int)((a + b - 1) / b); }

extern "C" void kernel_launch(void* const* d_in, const int* in_sizes, int n_in,
                              void* d_out, int out_size, void* d_ws, size_t ws_size,
                              hipStream_t stream) {
    const float* feat   = (const float*)d_in[0];
    const float* w_sub1 = (const float*)d_in[1];
    const float* w_down = (const float*)d_in[2];
    const float* w_sub2 = (const float*)d_in[3];
    const float* w_up   = (const float*)d_in[4];
    const float* w_sub3 = (const float*)d_in[5];
    const float* g1 = (const float*)d_in[6],  *b1 = (const float*)d_in[7];
    const float* g2 = (const float*)d_in[8],  *b2 = (const float*)d_in[9];
    const float* g3 = (const float*)d_in[10], *b3 = (const float*)d_in[11];
    const float* g4 = (const float*)d_in[12], *b4 = (const float*)d_in[13];
    const float* g5 = (const float*)d_in[14], *b5 = (const float*)d_in[15];
    const int* nbr_fine   = (const int*)d_in[16];
    const int* nbr_coarse = (const int*)d_in[17];
    const int* down_idx   = (const int*)d_in[18];
    const int* up_cidx    = (const int*)d_in[19];
    const int* up_k       = (const int*)d_in[20];

    const int N = in_sizes[0] / 32;
    const int M = in_sizes[17] / 27;
    const size_t maxr = (size_t)((N > M ? N : M) + 1);

    // rulebook caps (generous vs expected counts; append guarded by cap)
    const int cap_f = ((N / 4) + 127) & ~127;   // fine taps: ~2.4k expected
    const int cap_c = ((M / 2) + 127) & ~127;   // coarse taps: ~16k expected
    const int cap_d = cap_c;                    // down: ~N/8 per tap expected
    const int cap_u = cap_f;                    // up: ~N/8 per segment expected

    char* ws = (char*)d_ws;
    size_t off = 0;
    auto alloc = [&](size_t bytes) { void* p = ws + off; off += (bytes + 255) & ~(size_t)255; return p; };
    float* stats = (float*)alloc(1024 * sizeof(float));
    float* D  = (float*)alloc((size_t)N * 64 * sizeof(float));        // concat buf [skip|up]
    float* Cf = (float*)alloc((size_t)M * 64 * sizeof(float));        // coarse f32 temp
    unsigned short* FA = (unsigned short*)alloc(maxr * 64 * 2);
    unsigned short* FB = (unsigned short*)alloc(maxr * 64 * 2);
    int2* rb_fine   = (int2*)alloc((size_t)26 * cap_f * sizeof(int2));
    int2* rb_coarse = (int2*)alloc((size_t)26 * cap_c * sizeof(int2));
    int2* rb_down   = (int2*)alloc((size_t)8 * cap_d * sizeof(int2));
    int2* rb_up     = (int2*)alloc((size_t)8 * cap_u * sizeof(int2));
    unsigned short* w1t = (unsigned short*)alloc(27 * 32 * 32 * 2);
    unsigned short* wdt = (unsigned short*)alloc(8 * 32 * 64 * 2);
    unsigned short* w2t = (unsigned short*)alloc(27 * 64 * 64 * 2);
    unsigned short* w3t = (unsigned short*)alloc(27 * 64 * 32 * 2);
    unsigned short* wupT = (unsigned short*)alloc(8 * 64 * 32 * 2);

    float* st0 = stats + 0 * 128;
    float* st1 = stats + 1 * 128;   // conv1 out (32 ch)
    float* st2 = stats + 2 * 128;   // down out (64 ch)
    float* st3 = stats + 3 * 128;   // conv2 out (64 ch)
    float* st4 = stats + 4 * 128;   // deconv out (32 ch)
    int* cnts      = (int*)(stats + 768);
    int* cnt_fine   = cnts;          // 26
    int* cnt_coarse = cnts + 32;     // 26
    int* cnt_down   = cnts + 64;     // 8
    int* cnt_up     = cnts + 96;     // 8

    // ---- setup: zero stats/counters + Cf, weights, rulebooks ----
    zero_kernel<<<4, 256, 0, stream>>>(stats, 1024);
    zero_kernel<<<ceil_div((long)M * 64, 256), 256, 0, stream>>>(Cf, (long)M * 64);
    wt_transpose<32, 32><<<ceil_div(27 * 32 * 32, 256), 256, 0, stream>>>(w_sub1, w1t, 27);
    wt_transpose<32, 64><<<ceil_div(8 * 32 * 64, 256), 256, 0, stream>>>(w_down, wdt, 8);
    wt_transpose<64, 64><<<ceil_div(27 * 64 * 64, 256), 256, 0, stream>>>(w_sub2, w2t, 27);
    wt_transpose<64, 32><<<ceil_div(27 * 64 * 32, 256), 256, 0, stream>>>(w_sub3, w3t, 27);
    wt_transpose<64, 32><<<ceil_div(8 * 64 * 32, 256), 256, 0, stream>>>(w_up, wupT, 8);
    build_rb27<<<ceil_div(N, 256), 256, 0, stream>>>(nbr_fine, N, N, cap_f, rb_fine, cnt_fine);
    build_rb27<<<ceil_div(M, 256), 256, 0, stream>>>(nbr_coarse, M, M, cap_c, rb_coarse, cnt_coarse);
    build_rb8<<<ceil_div(M, 256), 256, 0, stream>>>(down_idx, M, N, cap_d, rb_down, cnt_down);
    build_rb_up<<<ceil_div(N, 256), 256, 0, stream>>>(up_cidx, up_k, N, cap_u, rb_up, cnt_up);

    // 1) BN0+ReLU(feat) -> FA [(N+1)x32 bf16]
    bn_stats<32><<<256, 256, 0, stream>>>(feat, N, 32, st0);
    bn_norm_relu_bf16<32, 32><<<ceil_div((long)(N + 1) * 4, 256), 256, 0, stream>>>(
        feat, N, 32, st0, st0, g1, b1, FA);
    // 2) conv1 (27, 32->32): center write + sparse atomics -> D[:,0:32]
    conv_center<32, 32><<<ceil_div(N, 128), 256, 0, stream>>>(
        FA, w1t + 13 * 32 * 32, D, N, N, 64);
    conv_sparse<32, 32, true><<<dim3(ceil_div(cap_f, 128), 26), 256, 0, stream>>>(
        FA, rb_fine, cnt_fine, w1t, D, cap_f, 13, N, 64);
    // 3) BN1+ReLU(skip) -> FB
    bn_stats<32><<<256, 256, 0, stream>>>(D, N, 64, st1);
    bn_norm_relu_bf16<32, 32><<<ceil_div((long)(N + 1) * 4, 256), 256, 0, stream>>>(
        D, N, 64, st1, st1, g2, b2, FB);
    // 4) down conv (8, 32->64): sparse atomics into zeroed Cf
    conv_sparse<32, 64, true><<<dim3(ceil_div(cap_d, 128), 8), 256, 0, stream>>>(
        FB, rb_down, cnt_down, wdt, Cf, cap_d, 99, N, 64);
    // 5) BN2+ReLU(Cf) -> FA [(M+1)x64]
    bn_stats<64><<<256, 256, 0, stream>>>(Cf, M, 64, st2);
    bn_norm_relu_bf16<64, 64><<<ceil_div((long)(M + 1) * 8, 256), 256, 0, stream>>>(
        Cf, M, 64, st2, st2, g3, b3, FA);
    // 6) conv2 (27, 64->64): center write + sparse atomics -> Cf (overwrite)
    conv_center<64, 64><<<ceil_div(M, 128), 256, 0, stream>>>(
        FA, w2t + 13 * 64 * 64, Cf, M, M, 64);
    conv_sparse<64, 64, true><<<dim3(ceil_div(cap_c, 128), 26), 256, 0, stream>>>(
        FA, rb_coarse, cnt_coarse, w2t, Cf, cap_c, 13, M, 64);
    // 7) BN3+ReLU(Cf) -> FB [(M+1)x64]
    bn_stats<64><<<256, 256, 0, stream>>>(Cf, M, 64, st3);
    bn_norm_relu_bf16<64, 64><<<ceil_div((long)(M + 1) * 8, 256), 256, 0, stream>>>(
        Cf, M, 64, st3, st3, g4, b4, FB);
    // 8) deconv (64->32): rulebook segments, direct writes -> D[:,32:64]
    conv_sparse<64, 32, false><<<dim3(ceil_div(cap_u, 128), 8), 256, 0, stream>>>(
        FB, rb_up, cnt_up, wupT, D + 32, cap_u, 99, M, 64);
    // 9) BN4+ReLU(D) -> FA [(N+1)x64]; low 32 ch stats = st1, high 32 = st4
    bn_stats<32><<<256, 256, 0, stream>>>(D + 32, N, 64, st4);
    bn_norm_relu_bf16<64, 32><<<ceil_div((long)(N + 1) * 8, 256), 256, 0, stream>>>(
        D, N, 64, st1, st4, g5, b5, FA);
    // 10) conv3 (27, 64->32): center write + sparse atomics -> d_out
    conv_center<64, 32><<<ceil_div(N, 128), 256, 0, stream>>>(
        FA, w3t + 13 * 64 * 32, (float*)d_out, N, N, 32);
    conv_sparse<64, 32, true><<<dim3(ceil_div(cap_f, 128), 26), 256, 0, stream>>>(
        FA, rb_fine, cnt_fine, w3t, (float*)d_out, cap_f, 13, N, 32);
}

// Round 8
// 1194.957 us; speedup vs baseline: 2.7817x; 2.7817x over previous
//
#include <hip/hip_runtime.h>

// ---------------------------------------------------------------------------
// Sparse UNet forward — round 8: rulebook sparse conv with wave-aggregated
//   rulebook builds (one atomicAdd per wave-256-rows per tap, ballot ranks).
//   Center tap -> dense GEMM writes; sparse taps -> rulebook MFMA + atomics;
//   deconv -> segmented rulebook, direct writes; down -> rulebook + atomics.
// ---------------------------------------------------------------------------

#define EPS 1e-4f

typedef __attribute__((ext_vector_type(8))) short short8;   // 8 x bf16
typedef __attribute__((ext_vector_type(4))) float f32x4;

__device__ __forceinline__ unsigned short f2bf(float f) {
    union { float f; unsigned int u; } v; v.f = f;
    unsigned int r = v.u + 0x7fffu + ((v.u >> 16) & 1u);   // RNE
    return (unsigned short)(r >> 16);
}

__global__ void zero_kernel(float* p, long n) {
    long i = (long)blockIdx.x * 256 + threadIdx.x;
    if (i < n) p[i] = 0.f;
}

// Per-channel sum / sumsq -> stats[0:C], stats[C:2C] (atomic accumulate).
template <int C>
__global__ __launch_bounds__(256) void bn_stats(const float* __restrict__ x,
                                                int rows, int stride,
                                                float* __restrict__ stats) {
    const int tid = threadIdx.x;
    const int c = tid & (C - 1);
    const int g = tid / C;
    const int GR = 256 / C;
    float s = 0.f, s2 = 0.f;
    for (int r = blockIdx.x * GR + g; r < rows; r += gridDim.x * GR) {
        float v = x[(size_t)r * stride + c];
        s += v; s2 += v * v;
    }
    __shared__ float sh[2][256];
    sh[0][tid] = s; sh[1][tid] = s2;
    __syncthreads();
    for (int off = 128; off >= C; off >>= 1) {
        if (tid < off) { sh[0][tid] += sh[0][tid + off]; sh[1][tid] += sh[1][tid + off]; }
        __syncthreads();
    }
    if (tid < C) {
        atomicAdd(&stats[c], sh[0][tid]);
        atomicAdd(&stats[C + c], sh[1][tid]);
    }
}

// BN finalize + ReLU -> bf16. Output packed (rows+1) x C, sentinel row zeroed.
template <int C, int CSPLIT>
__global__ __launch_bounds__(256) void bn_norm_relu_bf16(
    const float* __restrict__ x, int rows, int stride,
    const float* __restrict__ stA, const float* __restrict__ stB,
    const float* __restrict__ gamma, const float* __restrict__ beta,
    unsigned short* __restrict__ y) {
    constexpr int TPR = C / 8;
    int gid = blockIdx.x * 256 + threadIdx.x;
    int r = gid / TPR, t = gid % TPR;
    if (r > rows) return;
    short8 o8;
    if (r == rows) {
        for (int j = 0; j < 8; ++j) o8[j] = 0;
    } else {
        const float inv_n = 1.0f / (float)rows;
        const float* xr = x + (size_t)r * stride + t * 8;
        float4 v0 = *(const float4*)(xr);
        float4 v1 = *(const float4*)(xr + 4);
        float vv[8] = {v0.x, v0.y, v0.z, v0.w, v1.x, v1.y, v1.z, v1.w};
#pragma unroll
        for (int j = 0; j < 8; ++j) {
            int c = t * 8 + j;
            const float* st = (c < CSPLIT) ? stA : stB;
            int cc = (c < CSPLIT) ? c : c - CSPLIT;
            int cs = (c < CSPLIT) ? CSPLIT : (C - CSPLIT);
            float mu = st[cc] * inv_n;
            float var = st[cs + cc] * inv_n - mu * mu;
            float sc = gamma[c] * rsqrtf(var + EPS);
            float shf = beta[c] - mu * sc;
            float ov = fmaxf(0.f, fmaf(vv[j], sc, shf));
            o8[j] = (short)f2bf(ov);
        }
    }
    *(short8*)(y + (size_t)r * C + t * 8) = o8;
}

// W [K][CIN][COUT] f32 -> WT [K][COUT][CIN] bf16.
template <int CIN, int COUT>
__global__ void wt_transpose(const float* __restrict__ W, unsigned short* __restrict__ WT, int K) {
    int id = blockIdx.x * 256 + threadIdx.x;
    int total = K * CIN * COUT;
    if (id >= total) return;
    int t = id / (CIN * COUT);
    int r = id % (CIN * COUT);
    int co = r / CIN;
    int ci = r % CIN;
    WT[id] = f2bf(W[(size_t)t * CIN * COUT + ci * COUT + co]);
}

// ---- wave-aggregated rulebook builders -------------------------------------
// Each wave scans 256 consecutive rows (4 chunks of 64). Per tap: ballot masks
// per chunk, ONE leader atomicAdd of the wave total, lanes write at
// base + intra-wave rank. ~32x fewer global atomics than per-row appends.

__global__ __launch_bounds__(256) void build_rb27(
    const int* __restrict__ nbr, int rows, int P, int cap,
    int2* __restrict__ rb, int* __restrict__ cnt) {
    const int lane = threadIdx.x & 63;
    const int wave = threadIdx.x >> 6;
    const long wbase = ((long)blockIdx.x * 4 + wave) * 256;
    if (wbase >= rows) return;
    for (int kk = 0; kk < 26; ++kk) {
        const int k = kk + (kk >= 13 ? 1 : 0);
        const int* nk = nbr + (size_t)k * rows;
        unsigned long long masks[4];
        int vs[4], tot[4], total = 0;
#pragma unroll
        for (int c = 0; c < 4; ++c) {
            long m = wbase + c * 64 + lane;
            int v = (m < rows) ? nk[m] : P;
            vs[c] = v;
            masks[c] = __ballot(v != P);
            tot[c] = __popcll(masks[c]);
            total += tot[c];
        }
        if (total == 0) continue;
        int base = 0;
        if (lane == 0) base = atomicAdd(&cnt[kk], total);
        base = __shfl(base, 0);
#pragma unroll
        for (int c = 0; c < 4; ++c) {
            if (vs[c] != P) {
                int rank = __popcll(masks[c] & ((1ull << lane) - 1ull));
                int j = base + rank;
                if (j < cap)
                    rb[(size_t)kk * cap + j] = make_int2((int)(wbase + c * 64 + lane), vs[c]);
            }
            base += tot[c];
        }
    }
}

__global__ __launch_bounds__(256) void build_rb8(
    const int* __restrict__ nbr, int rows, int P, int cap,
    int2* __restrict__ rb, int* __restrict__ cnt) {
    const int lane = threadIdx.x & 63;
    const int wave = threadIdx.x >> 6;
    const long wbase = ((long)blockIdx.x * 4 + wave) * 256;
    if (wbase >= rows) return;
    for (int k = 0; k < 8; ++k) {
        const int* nk = nbr + (size_t)k * rows;
        unsigned long long masks[4];
        int vs[4], tot[4], total = 0;
#pragma unroll
        for (int c = 0; c < 4; ++c) {
            long m = wbase + c * 64 + lane;
            int v = (m < rows) ? nk[m] : P;
            vs[c] = v;
            masks[c] = __ballot(v != P);
            tot[c] = __popcll(masks[c]);
            total += tot[c];
        }
        if (total == 0) continue;
        int base = 0;
        if (lane == 0) base = atomicAdd(&cnt[k], total);
        base = __shfl(base, 0);
#pragma unroll
        for (int c = 0; c < 4; ++c) {
            if (vs[c] != P) {
                int rank = __popcll(masks[c] & ((1ull << lane) - 1ull));
                int j = base + rank;
                if (j < cap)
                    rb[(size_t)k * cap + j] = make_int2((int)(wbase + c * 64 + lane), vs[c]);
            }
            base += tot[c];
        }
    }
}

__global__ __launch_bounds__(256) void build_rb_up(
    const int* __restrict__ up_cidx, const int* __restrict__ up_k,
    int rows, int cap, int2* __restrict__ rb, int* __restrict__ cnt) {
    const int lane = threadIdx.x & 63;
    const int wave = threadIdx.x >> 6;
    const long wbase = ((long)blockIdx.x * 4 + wave) * 256;
    if (wbase >= rows) return;
    int segs[4], cs[4];
#pragma unroll
    for (int c = 0; c < 4; ++c) {
        long i = wbase + c * 64 + lane;
        segs[c] = (i < rows) ? up_k[i] : -1;
        cs[c] = (i < rows) ? up_cidx[i] : 0;
    }
    for (int s = 0; s < 8; ++s) {
        unsigned long long masks[4];
        int tot[4], total = 0;
#pragma unroll
        for (int c = 0; c < 4; ++c) {
            masks[c] = __ballot(segs[c] == s);
            tot[c] = __popcll(masks[c]);
            total += tot[c];
        }
        if (total == 0) continue;
        int base = 0;
        if (lane == 0) base = atomicAdd(&cnt[s], total);
        base = __shfl(base, 0);
#pragma unroll
        for (int c = 0; c < 4; ++c) {
            if (segs[c] == s) {
                int rank = __popcll(masks[c] & ((1ull << lane) - 1ull));
                int j = base + rank;
                if (j < cap)
                    rb[(size_t)s * cap + j] = make_int2((int)(wbase + c * 64 + lane), cs[c]);
            }
            base += tot[c];
        }
    }
}

// ---- conv kernels ----------------------------------------------------------

// Dense center-tap GEMM (identity gather): out[m] = fpad[m] @ Wk, plain write.
template <int CIN, int COT>
__global__ __launch_bounds__(256) void conv_center(
    const unsigned short* __restrict__ fpad,
    const unsigned short* __restrict__ Wk,     // [COT][CIN] bf16 (center slice)
    float* __restrict__ out, int rows, int P, int out_stride) {
    constexpr int N_SUB = COT / 16;
    constexpr int K_SUB = CIN / 32;
    const int tid = threadIdx.x;
    const int wave = tid >> 6;
    const int lane = tid & 63;
    const int q = lane >> 4;
    const int l15 = lane & 15;
    const int m0 = blockIdx.x * 128 + wave * 32;

    f32x4 acc[2][N_SUB];
#pragma unroll
    for (int mt = 0; mt < 2; ++mt)
#pragma unroll
        for (int nt = 0; nt < N_SUB; ++nt) acc[mt][nt] = (f32x4){0.f, 0.f, 0.f, 0.f};

    short8 a[2][K_SUB], b[N_SUB][K_SUB];
#pragma unroll
    for (int mt = 0; mt < 2; ++mt) {
        int m = m0 + mt * 16 + l15;
        int src = (m < rows) ? m : P;
#pragma unroll
        for (int kf = 0; kf < K_SUB; ++kf)
            a[mt][kf] = *(const short8*)(fpad + (size_t)src * CIN + kf * 32 + q * 8);
    }
#pragma unroll
    for (int nt = 0; nt < N_SUB; ++nt)
#pragma unroll
        for (int kf = 0; kf < K_SUB; ++kf)
            b[nt][kf] = *(const short8*)(Wk + (size_t)(nt * 16 + l15) * CIN + kf * 32 + q * 8);
#pragma unroll
    for (int mt = 0; mt < 2; ++mt)
#pragma unroll
        for (int nt = 0; nt < N_SUB; ++nt)
#pragma unroll
            for (int kf = 0; kf < K_SUB; ++kf)
                acc[mt][nt] = __builtin_amdgcn_mfma_f32_16x16x32_bf16(
                    a[mt][kf], b[nt][kf], acc[mt][nt], 0, 0, 0);
#pragma unroll
    for (int mt = 0; mt < 2; ++mt)
#pragma unroll
        for (int i = 0; i < 4; ++i) {
            int row = m0 + mt * 16 + q * 4 + i;
            if (row < rows) {
#pragma unroll
                for (int nt = 0; nt < N_SUB; ++nt)
                    out[(size_t)row * out_stride + nt * 16 + l15] = acc[mt][nt][i];
            }
        }
}

// Sparse-tap gather-GEMM over compacted rulebook tiles.
template <int CIN, int COT, bool ATOMIC>
__global__ __launch_bounds__(256) void conv_sparse(
    const unsigned short* __restrict__ fpad,
    const int2* __restrict__ rb,
    const int* __restrict__ cnt,
    const unsigned short* __restrict__ WT,
    float* __restrict__ out,
    int cap, int kskip, int P, int out_stride) {
    constexpr int N_SUB = COT / 16;
    constexpr int K_SUB = CIN / 32;
    const int tap = blockIdx.y;
    int n = cnt[tap];
    n = n < cap ? n : cap;
    const int base0 = blockIdx.x * 128;
    if (base0 >= n) return;
    const int k = tap + (tap >= kskip ? 1 : 0);
    const int tid = threadIdx.x;
    const int wave = tid >> 6;
    const int lane = tid & 63;
    const int q = lane >> 4;
    const int l15 = lane & 15;
    const int base = base0 + wave * 32;
    const int2* seg = rb + (size_t)tap * cap;

    f32x4 acc[2][N_SUB];
#pragma unroll
    for (int mt = 0; mt < 2; ++mt)
#pragma unroll
        for (int nt = 0; nt < N_SUB; ++nt) acc[mt][nt] = (f32x4){0.f, 0.f, 0.f, 0.f};

    short8 a[2][K_SUB], b[N_SUB][K_SUB];
#pragma unroll
    for (int mt = 0; mt < 2; ++mt) {
        int j = base + mt * 16 + l15;
        int src = (j < n) ? seg[j].y : P;
#pragma unroll
        for (int kf = 0; kf < K_SUB; ++kf)
            a[mt][kf] = *(const short8*)(fpad + (size_t)src * CIN + kf * 32 + q * 8);
    }
    const unsigned short* Wk = WT + (size_t)k * COT * CIN;
#pragma unroll
    for (int nt = 0; nt < N_SUB; ++nt)
#pragma unroll
        for (int kf = 0; kf < K_SUB; ++kf)
            b[nt][kf] = *(const short8*)(Wk + (size_t)(nt * 16 + l15) * CIN + kf * 32 + q * 8);
#pragma unroll
    for (int mt = 0; mt < 2; ++mt)
#pragma unroll
        for (int nt = 0; nt < N_SUB; ++nt)
#pragma unroll
            for (int kf = 0; kf < K_SUB; ++kf)
                acc[mt][nt] = __builtin_amdgcn_mfma_f32_16x16x32_bf16(
                    a[mt][kf], b[nt][kf], acc[mt][nt], 0, 0, 0);

#pragma unroll
    for (int mt = 0; mt < 2; ++mt)
#pragma unroll
        for (int i = 0; i < 4; ++i) {
            int j = base + mt * 16 + q * 4 + i;
            if (j < n) {
                int row = seg[j].x;
                float* o = out + (size_t)row * out_stride + l15;
#pragma unroll
                for (int nt = 0; nt < N_SUB; ++nt) {
                    if (ATOMIC) atomicAdd(o + nt * 16, acc[mt][nt][i]);
                    else        o[nt * 16] = acc[mt][nt][i];
                }
            }
        }
}

static inline int ceil_div(long a, long b) { return (int)((a + b - 1) / b); }

extern "C" void kernel_launch(void* const* d_in, const int* in_sizes, int n_in,
                              void* d_out, int out_size, void* d_ws, size_t ws_size,
                              hipStream_t stream) {
    const float* feat   = (const float*)d_in[0];
    const float* w_sub1 = (const float*)d_in[1];
    const float* w_down = (const float*)d_in[2];
    const float* w_sub2 = (const float*)d_in[3];
    const float* w_up   = (const float*)d_in[4];
    const float* w_sub3 = (const float*)d_in[5];
    const float* g1 = (const float*)d_in[6],  *b1 = (const float*)d_in[7];
    const float* g2 = (const float*)d_in[8],  *b2 = (const float*)d_in[9];
    const float* g3 = (const float*)d_in[10], *b3 = (const float*)d_in[11];
    const float* g4 = (const float*)d_in[12], *b4 = (const float*)d_in[13];
    const float* g5 = (const float*)d_in[14], *b5 = (const float*)d_in[15];
    const int* nbr_fine   = (const int*)d_in[16];
    const int* nbr_coarse = (const int*)d_in[17];
    const int* down_idx   = (const int*)d_in[18];
    const int* up_cidx    = (const int*)d_in[19];
    const int* up_k       = (const int*)d_in[20];

    const int N = in_sizes[0] / 32;
    const int M = in_sizes[17] / 27;
    const size_t maxr = (size_t)((N > M ? N : M) + 1);

    // rulebook caps (expected: fine ~N*0.012=2.4k; coarse ~M*0.092=17.5k;
    // down/up ~N/8=25k per tap). Margins 2.6-6.8x; builders guard overflow.
    const int cap_f = 16384;
    const int cap_c = 49152;
    const int cap_d = 32768;
    const int cap_u = 32768;

    char* ws = (char*)d_ws;
    size_t off = 0;
    auto alloc = [&](size_t bytes) { void* p = ws + off; off += (bytes + 255) & ~(size_t)255; return p; };
    float* stats = (float*)alloc(1024 * sizeof(float));
    float* D  = (float*)alloc((size_t)N * 64 * sizeof(float));        // concat buf [skip|up]
    float* Cf = (float*)alloc((size_t)M * 64 * sizeof(float));        // coarse f32 temp
    unsigned short* FA = (unsigned short*)alloc(maxr * 64 * 2);
    unsigned short* FB = (unsigned short*)alloc(maxr * 64 * 2);
    int2* rb_fine   = (int2*)alloc((size_t)26 * cap_f * sizeof(int2));
    int2* rb_coarse = (int2*)alloc((size_t)26 * cap_c * sizeof(int2));
    int2* rb_down   = (int2*)alloc((size_t)8 * cap_d * sizeof(int2));
    int2* rb_up     = (int2*)alloc((size_t)8 * cap_u * sizeof(int2));
    unsigned short* w1t = (unsigned short*)alloc(27 * 32 * 32 * 2);
    unsigned short* wdt = (unsigned short*)alloc(8 * 32 * 64 * 2);
    unsigned short* w2t = (unsigned short*)alloc(27 * 64 * 64 * 2);
    unsigned short* w3t = (unsigned short*)alloc(27 * 64 * 32 * 2);
    unsigned short* wupT = (unsigned short*)alloc(8 * 64 * 32 * 2);

    float* st0 = stats + 0 * 128;
    float* st1 = stats + 1 * 128;   // conv1 out (32 ch)
    float* st2 = stats + 2 * 128;   // down out (64 ch)
    float* st3 = stats + 3 * 128;   // conv2 out (64 ch)
    float* st4 = stats + 4 * 128;   // deconv out (32 ch)
    int* cnts       = (int*)(stats + 768);
    int* cnt_fine   = cnts;          // 26
    int* cnt_coarse = cnts + 32;     // 26
    int* cnt_down   = cnts + 64;     // 8
    int* cnt_up     = cnts + 96;     // 8

    // ---- setup: zero stats/counters + Cf, weights, rulebooks ----
    zero_kernel<<<4, 256, 0, stream>>>(stats, 1024);
    zero_kernel<<<ceil_div((long)M * 64, 256), 256, 0, stream>>>(Cf, (long)M * 64);
    wt_transpose<32, 32><<<ceil_div(27 * 32 * 32, 256), 256, 0, stream>>>(w_sub1, w1t, 27);
    wt_transpose<32, 64><<<ceil_div(8 * 32 * 64, 256), 256, 0, stream>>>(w_down, wdt, 8);
    wt_transpose<64, 64><<<ceil_div(27 * 64 * 64, 256), 256, 0, stream>>>(w_sub2, w2t, 27);
    wt_transpose<64, 32><<<ceil_div(27 * 64 * 32, 256), 256, 0, stream>>>(w_sub3, w3t, 27);
    wt_transpose<64, 32><<<ceil_div(8 * 64 * 32, 256), 256, 0, stream>>>(w_up, wupT, 8);
    build_rb27<<<ceil_div(N, 1024), 256, 0, stream>>>(nbr_fine, N, N, cap_f, rb_fine, cnt_fine);
    build_rb27<<<ceil_div(M, 1024), 256, 0, stream>>>(nbr_coarse, M, M, cap_c, rb_coarse, cnt_coarse);
    build_rb8<<<ceil_div(M, 1024), 256, 0, stream>>>(down_idx, M, N, cap_d, rb_down, cnt_down);
    build_rb_up<<<ceil_div(N, 1024), 256, 0, stream>>>(up_cidx, up_k, N, cap_u, rb_up, cnt_up);

    // 1) BN0+ReLU(feat) -> FA [(N+1)x32 bf16]
    bn_stats<32><<<256, 256, 0, stream>>>(feat, N, 32, st0);
    bn_norm_relu_bf16<32, 32><<<ceil_div((long)(N + 1) * 4, 256), 256, 0, stream>>>(
        feat, N, 32, st0, st0, g1, b1, FA);
    // 2) conv1 (27, 32->32): center write + sparse atomics -> D[:,0:32]
    conv_center<32, 32><<<ceil_div(N, 128), 256, 0, stream>>>(
        FA, w1t + 13 * 32 * 32, D, N, N, 64);
    conv_sparse<32, 32, true><<<dim3(ceil_div(cap_f, 128), 26), 256, 0, stream>>>(
        FA, rb_fine, cnt_fine, w1t, D, cap_f, 13, N, 64);
    // 3) BN1+ReLU(skip) -> FB
    bn_stats<32><<<256, 256, 0, stream>>>(D, N, 64, st1);
    bn_norm_relu_bf16<32, 32><<<ceil_div((long)(N + 1) * 4, 256), 256, 0, stream>>>(
        D, N, 64, st1, st1, g2, b2, FB);
    // 4) down conv (8, 32->64): sparse atomics into zeroed Cf
    conv_sparse<32, 64, true><<<dim3(ceil_div(cap_d, 128), 8), 256, 0, stream>>>(
        FB, rb_down, cnt_down, wdt, Cf, cap_d, 99, N, 64);
    // 5) BN2+ReLU(Cf) -> FA [(M+1)x64]
    bn_stats<64><<<256, 256, 0, stream>>>(Cf, M, 64, st2);
    bn_norm_relu_bf16<64, 64><<<ceil_div((long)(M + 1) * 8, 256), 256, 0, stream>>>(
        Cf, M, 64, st2, st2, g3, b3, FA);
    // 6) conv2 (27, 64->64): center write + sparse atomics -> Cf (overwrite)
    conv_center<64, 64><<<ceil_div(M, 128), 256, 0, stream>>>(
        FA, w2t + 13 * 64 * 64, Cf, M, M, 64);
    conv_sparse<64, 64, true><<<dim3(ceil_div(cap_c, 128), 26), 256, 0, stream>>>(
        FA, rb_coarse, cnt_coarse, w2t, Cf, cap_c, 13, M, 64);
    // 7) BN3+ReLU(Cf) -> FB [(M+1)x64]
    bn_stats<64><<<256, 256, 0, stream>>>(Cf, M, 64, st3);
    bn_norm_relu_bf16<64, 64><<<ceil_div((long)(M + 1) * 8, 256), 256, 0, stream>>>(
        Cf, M, 64, st3, st3, g4, b4, FB);
    // 8) deconv (64->32): rulebook segments, direct writes -> D[:,32:64]
    conv_sparse<64, 32, false><<<dim3(ceil_div(cap_u, 128), 8), 256, 0, stream>>>(
        FB, rb_up, cnt_up, wupT, D + 32, cap_u, 99, M, 64);
    // 9) BN4+ReLU(D) -> FA [(N+1)x64]; low 32 ch stats = st1, high 32 = st4
    bn_stats<32><<<256, 256, 0, stream>>>(D + 32, N, 64, st4);
    bn_norm_relu_bf16<64, 32><<<ceil_div((long)(N + 1) * 8, 256), 256, 0, stream>>>(
        D, N, 64, st1, st4, g5, b5, FA);
    // 10) conv3 (27, 64->32): center write + sparse atomics -> d_out
    conv_center<64, 32><<<ceil_div(N, 128), 256, 0, stream>>>(
        FA, w3t + 13 * 64 * 32, (float*)d_out, N, N, 32);
    conv_sparse<64, 32, true><<<dim3(ceil_div(cap_f, 128), 26), 256, 0, stream>>>(
        FA, rb_fine, cnt_fine, w3t, (float*)d_out, cap_f, 13, N, 32);
}

// Round 9
// 691.022 us; speedup vs baseline: 4.8102x; 1.7293x over previous
//
#include <hip/hip_runtime.h>

// ---------------------------------------------------------------------------
// Sparse UNet forward — round 9: rulebook sparse conv, fixed builders.
//   Builders: grid=(chunks, taps), block-level aggregation (1 atomic/block),
//   counters padded to one cacheline per tap (cnt[tap*32]).
// ---------------------------------------------------------------------------

#define EPS 1e-4f

typedef __attribute__((ext_vector_type(8))) short short8;   // 8 x bf16
typedef __attribute__((ext_vector_type(4))) float f32x4;

__device__ __forceinline__ unsigned short f2bf(float f) {
    union { float f; unsigned int u; } v; v.f = f;
    unsigned int r = v.u + 0x7fffu + ((v.u >> 16) & 1u);   // RNE
    return (unsigned short)(r >> 16);
}

__global__ void zero_kernel(float* p, long n) {
    long i = (long)blockIdx.x * 256 + threadIdx.x;
    if (i < n) p[i] = 0.f;
}

// Per-channel sum / sumsq -> stats[0:C], stats[C:2C] (atomic accumulate).
template <int C>
__global__ __launch_bounds__(256) void bn_stats(const float* __restrict__ x,
                                                int rows, int stride,
                                                float* __restrict__ stats) {
    const int tid = threadIdx.x;
    const int c = tid & (C - 1);
    const int g = tid / C;
    const int GR = 256 / C;
    float s = 0.f, s2 = 0.f;
    for (int r = blockIdx.x * GR + g; r < rows; r += gridDim.x * GR) {
        float v = x[(size_t)r * stride + c];
        s += v; s2 += v * v;
    }
    __shared__ float sh[2][256];
    sh[0][tid] = s; sh[1][tid] = s2;
    __syncthreads();
    for (int off = 128; off >= C; off >>= 1) {
        if (tid < off) { sh[0][tid] += sh[0][tid + off]; sh[1][tid] += sh[1][tid + off]; }
        __syncthreads();
    }
    if (tid < C) {
        atomicAdd(&stats[c], sh[0][tid]);
        atomicAdd(&stats[C + c], sh[1][tid]);
    }
}

// BN finalize + ReLU -> bf16. Output packed (rows+1) x C, sentinel row zeroed.
template <int C, int CSPLIT>
__global__ __launch_bounds__(256) void bn_norm_relu_bf16(
    const float* __restrict__ x, int rows, int stride,
    const float* __restrict__ stA, const float* __restrict__ stB,
    const float* __restrict__ gamma, const float* __restrict__ beta,
    unsigned short* __restrict__ y) {
    constexpr int TPR = C / 8;
    int gid = blockIdx.x * 256 + threadIdx.x;
    int r = gid / TPR, t = gid % TPR;
    if (r > rows) return;
    short8 o8;
    if (r == rows) {
        for (int j = 0; j < 8; ++j) o8[j] = 0;
    } else {
        const float inv_n = 1.0f / (float)rows;
        const float* xr = x + (size_t)r * stride + t * 8;
        float4 v0 = *(const float4*)(xr);
        float4 v1 = *(const float4*)(xr + 4);
        float vv[8] = {v0.x, v0.y, v0.z, v0.w, v1.x, v1.y, v1.z, v1.w};
#pragma unroll
        for (int j = 0; j < 8; ++j) {
            int c = t * 8 + j;
            const float* st = (c < CSPLIT) ? stA : stB;
            int cc = (c < CSPLIT) ? c : c - CSPLIT;
            int cs = (c < CSPLIT) ? CSPLIT : (C - CSPLIT);
            float mu = st[cc] * inv_n;
            float var = st[cs + cc] * inv_n - mu * mu;
            float sc = gamma[c] * rsqrtf(var + EPS);
            float shf = beta[c] - mu * sc;
            float ov = fmaxf(0.f, fmaf(vv[j], sc, shf));
            o8[j] = (short)f2bf(ov);
        }
    }
    *(short8*)(y + (size_t)r * C + t * 8) = o8;
}

// W [K][CIN][COUT] f32 -> WT [K][COUT][CIN] bf16.
template <int CIN, int COUT>
__global__ void wt_transpose(const float* __restrict__ W, unsigned short* __restrict__ WT, int K) {
    int id = blockIdx.x * 256 + threadIdx.x;
    int total = K * CIN * COUT;
    if (id >= total) return;
    int t = id / (CIN * COUT);
    int r = id % (CIN * COUT);
    int co = r / CIN;
    int ci = r % CIN;
    WT[id] = f2bf(W[(size_t)t * CIN * COUT + ci * COUT + co]);
}

// ---- rulebook builders -----------------------------------------------------
// grid = (row chunks of 1024, compact taps). Block handles ONE tap column.
// Per wave: 4x ballot over 256 rows; block total via LDS; ONE atomicAdd per
// block into cnt[tap*32] (one cacheline per tap); ranks from ballot masks.

__global__ __launch_bounds__(256) void build_rb_tap(
    const int* __restrict__ nbr, int rows, int P, int cap, int kskip,
    int2* __restrict__ rb, int* __restrict__ cnt) {
    const int tap = blockIdx.y;
    const int k = tap + (tap >= kskip ? 1 : 0);
    const int* nk = nbr + (size_t)k * rows;
    const int lane = threadIdx.x & 63;
    const int wave = threadIdx.x >> 6;
    const long wbase = (long)blockIdx.x * 1024 + wave * 256;

    unsigned long long masks[4];
    int vs[4], tot[4], wtotal = 0;
#pragma unroll
    for (int c = 0; c < 4; ++c) {
        long m = wbase + c * 64 + lane;
        int v = (m < rows) ? nk[m] : P;
        vs[c] = v;
        masks[c] = __ballot(v != P);
        tot[c] = __popcll(masks[c]);
        wtotal += tot[c];
    }
    __shared__ int sh[5];
    if (lane == 0) sh[wave] = wtotal;
    __syncthreads();
    if (threadIdx.x == 0) {
        int t = sh[0] + sh[1] + sh[2] + sh[3];
        sh[4] = t ? atomicAdd(&cnt[tap * 32], t) : 0;
    }
    __syncthreads();
    int base = sh[4];
    for (int w = 0; w < wave; ++w) base += sh[w];   // small (4 iters max)
#pragma unroll
    for (int c = 0; c < 4; ++c) {
        if (vs[c] != P) {
            int rank = __popcll(masks[c] & ((1ull << lane) - 1ull));
            int j = base + rank;
            if (j < cap)
                rb[(size_t)tap * cap + j] = make_int2((int)(wbase + c * 64 + lane), vs[c]);
        }
        base += tot[c];
    }
}

// Deconv builder: segment fine rows by up_k. grid = (chunks, 8 segments).
__global__ __launch_bounds__(256) void build_rb_up(
    const int* __restrict__ up_cidx, const int* __restrict__ up_k,
    int rows, int cap, int2* __restrict__ rb, int* __restrict__ cnt) {
    const int s = blockIdx.y;
    const int lane = threadIdx.x & 63;
    const int wave = threadIdx.x >> 6;
    const long wbase = (long)blockIdx.x * 1024 + wave * 256;

    unsigned long long masks[4];
    int cs[4], ok[4], tot[4], wtotal = 0;
#pragma unroll
    for (int c = 0; c < 4; ++c) {
        long i = wbase + c * 64 + lane;
        int seg = (i < rows) ? up_k[i] : -1;
        cs[c] = (i < rows) ? up_cidx[i] : 0;
        ok[c] = (seg == s);
        masks[c] = __ballot(ok[c]);
        tot[c] = __popcll(masks[c]);
        wtotal += tot[c];
    }
    __shared__ int sh[5];
    if (lane == 0) sh[wave] = wtotal;
    __syncthreads();
    if (threadIdx.x == 0) {
        int t = sh[0] + sh[1] + sh[2] + sh[3];
        sh[4] = t ? atomicAdd(&cnt[s * 32], t) : 0;
    }
    __syncthreads();
    int base = sh[4];
    for (int w = 0; w < wave; ++w) base += sh[w];
#pragma unroll
    for (int c = 0; c < 4; ++c) {
        if (ok[c]) {
            int rank = __popcll(masks[c] & ((1ull << lane) - 1ull));
            int j = base + rank;
            if (j < cap)
                rb[(size_t)s * cap + j] = make_int2((int)(wbase + c * 64 + lane), cs[c]);
        }
        base += tot[c];
    }
}

// ---- conv kernels ----------------------------------------------------------

// Dense center-tap GEMM (identity gather): out[m] = fpad[m] @ Wk, plain write.
template <int CIN, int COT>
__global__ __launch_bounds__(256) void conv_center(
    const unsigned short* __restrict__ fpad,
    const unsigned short* __restrict__ Wk,     // [COT][CIN] bf16 (center slice)
    float* __restrict__ out, int rows, int P, int out_stride) {
    constexpr int N_SUB = COT / 16;
    constexpr int K_SUB = CIN / 32;
    const int tid = threadIdx.x;
    const int wave = tid >> 6;
    const int lane = tid & 63;
    const int q = lane >> 4;
    const int l15 = lane & 15;
    const int m0 = blockIdx.x * 128 + wave * 32;

    f32x4 acc[2][N_SUB];
#pragma unroll
    for (int mt = 0; mt < 2; ++mt)
#pragma unroll
        for (int nt = 0; nt < N_SUB; ++nt) acc[mt][nt] = (f32x4){0.f, 0.f, 0.f, 0.f};

    short8 a[2][K_SUB], b[N_SUB][K_SUB];
#pragma unroll
    for (int mt = 0; mt < 2; ++mt) {
        int m = m0 + mt * 16 + l15;
        int src = (m < rows) ? m : P;
#pragma unroll
        for (int kf = 0; kf < K_SUB; ++kf)
            a[mt][kf] = *(const short8*)(fpad + (size_t)src * CIN + kf * 32 + q * 8);
    }
#pragma unroll
    for (int nt = 0; nt < N_SUB; ++nt)
#pragma unroll
        for (int kf = 0; kf < K_SUB; ++kf)
            b[nt][kf] = *(const short8*)(Wk + (size_t)(nt * 16 + l15) * CIN + kf * 32 + q * 8);
#pragma unroll
    for (int mt = 0; mt < 2; ++mt)
#pragma unroll
        for (int nt = 0; nt < N_SUB; ++nt)
#pragma unroll
            for (int kf = 0; kf < K_SUB; ++kf)
                acc[mt][nt] = __builtin_amdgcn_mfma_f32_16x16x32_bf16(
                    a[mt][kf], b[nt][kf], acc[mt][nt], 0, 0, 0);
#pragma unroll
    for (int mt = 0; mt < 2; ++mt)
#pragma unroll
        for (int i = 0; i < 4; ++i) {
            int row = m0 + mt * 16 + q * 4 + i;
            if (row < rows) {
#pragma unroll
                for (int nt = 0; nt < N_SUB; ++nt)
                    out[(size_t)row * out_stride + nt * 16 + l15] = acc[mt][nt][i];
            }
        }
}

// Sparse-tap gather-GEMM over compacted rulebook tiles.
template <int CIN, int COT, bool ATOMIC>
__global__ __launch_bounds__(256) void conv_sparse(
    const unsigned short* __restrict__ fpad,
    const int2* __restrict__ rb,
    const int* __restrict__ cnt,
    const unsigned short* __restrict__ WT,
    float* __restrict__ out,
    int cap, int kskip, int P, int out_stride) {
    constexpr int N_SUB = COT / 16;
    constexpr int K_SUB = CIN / 32;
    const int tap = blockIdx.y;
    int n = cnt[tap * 32];
    n = n < cap ? n : cap;
    const int base0 = blockIdx.x * 128;
    if (base0 >= n) return;
    const int k = tap + (tap >= kskip ? 1 : 0);
    const int tid = threadIdx.x;
    const int wave = tid >> 6;
    const int lane = tid & 63;
    const int q = lane >> 4;
    const int l15 = lane & 15;
    const int base = base0 + wave * 32;
    const int2* seg = rb + (size_t)tap * cap;

    f32x4 acc[2][N_SUB];
#pragma unroll
    for (int mt = 0; mt < 2; ++mt)
#pragma unroll
        for (int nt = 0; nt < N_SUB; ++nt) acc[mt][nt] = (f32x4){0.f, 0.f, 0.f, 0.f};

    short8 a[2][K_SUB], b[N_SUB][K_SUB];
#pragma unroll
    for (int mt = 0; mt < 2; ++mt) {
        int j = base + mt * 16 + l15;
        int src = (j < n) ? seg[j].y : P;
#pragma unroll
        for (int kf = 0; kf < K_SUB; ++kf)
            a[mt][kf] = *(const short8*)(fpad + (size_t)src * CIN + kf * 32 + q * 8);
    }
    const unsigned short* Wk = WT + (size_t)k * COT * CIN;
#pragma unroll
    for (int nt = 0; nt < N_SUB; ++nt)
#pragma unroll
        for (int kf = 0; kf < K_SUB; ++kf)
            b[nt][kf] = *(const short8*)(Wk + (size_t)(nt * 16 + l15) * CIN + kf * 32 + q * 8);
#pragma unroll
    for (int mt = 0; mt < 2; ++mt)
#pragma unroll
        for (int nt = 0; nt < N_SUB; ++nt)
#pragma unroll
            for (int kf = 0; kf < K_SUB; ++kf)
                acc[mt][nt] = __builtin_amdgcn_mfma_f32_16x16x32_bf16(
                    a[mt][kf], b[nt][kf], acc[mt][nt], 0, 0, 0);

#pragma unroll
    for (int mt = 0; mt < 2; ++mt)
#pragma unroll
        for (int i = 0; i < 4; ++i) {
            int j = base + mt * 16 + q * 4 + i;
            if (j < n) {
                int row = seg[j].x;
                float* o = out + (size_t)row * out_stride + l15;
#pragma unroll
                for (int nt = 0; nt < N_SUB; ++nt) {
                    if (ATOMIC) atomicAdd(o + nt * 16, acc[mt][nt][i]);
                    else        o[nt * 16] = acc[mt][nt][i];
                }
            }
        }
}

static inline int ceil_div(long a, long b) { return (int)((a + b - 1) / b); }

extern "C" void kernel_launch(void* const* d_in, const int* in_sizes, int n_in,
                              void* d_out, int out_size, void* d_ws, size_t ws_size,
                              hipStream_t stream) {
    const float* feat   = (const float*)d_in[0];
    const float* w_sub1 = (const float*)d_in[1];
    const float* w_down = (const float*)d_in[2];
    const float* w_sub2 = (const float*)d_in[3];
    const float* w_up   = (const float*)d_in[4];
    const float* w_sub3 = (const float*)d_in[5];
    const float* g1 = (const float*)d_in[6],  *b1 = (const float*)d_in[7];
    const float* g2 = (const float*)d_in[8],  *b2 = (const float*)d_in[9];
    const float* g3 = (const float*)d_in[10], *b3 = (const float*)d_in[11];
    const float* g4 = (const float*)d_in[12], *b4 = (const float*)d_in[13];
    const float* g5 = (const float*)d_in[14], *b5 = (const float*)d_in[15];
    const int* nbr_fine   = (const int*)d_in[16];
    const int* nbr_coarse = (const int*)d_in[17];
    const int* down_idx   = (const int*)d_in[18];
    const int* up_cidx    = (const int*)d_in[19];
    const int* up_k       = (const int*)d_in[20];

    const int N = in_sizes[0] / 32;
    const int M = in_sizes[17] / 27;
    const size_t maxr = (size_t)((N > M ? N : M) + 1);

    // rulebook caps (expected: fine ~2.4k/tap; coarse ~17.5k; down/up ~25k).
    const int cap_f = 16384;
    const int cap_c = 49152;
    const int cap_d = 32768;
    const int cap_u = 32768;

    char* ws = (char*)d_ws;
    size_t off = 0;
    auto alloc = [&](size_t bytes) { void* p = ws + off; off += (bytes + 255) & ~(size_t)255; return p; };
    float* stats = (float*)alloc(768 * sizeof(float));
    int*   cnts  = (int*)alloc(4096 * sizeof(int));   // padded: 32 ints/tap
    float* D  = (float*)alloc((size_t)N * 64 * sizeof(float));        // concat buf [skip|up]
    float* Cf = (float*)alloc((size_t)M * 64 * sizeof(float));        // coarse f32 temp
    unsigned short* FA = (unsigned short*)alloc(maxr * 64 * 2);
    unsigned short* FB = (unsigned short*)alloc(maxr * 64 * 2);
    int2* rb_fine   = (int2*)alloc((size_t)26 * cap_f * sizeof(int2));
    int2* rb_coarse = (int2*)alloc((size_t)26 * cap_c * sizeof(int2));
    int2* rb_down   = (int2*)alloc((size_t)8 * cap_d * sizeof(int2));
    int2* rb_up     = (int2*)alloc((size_t)8 * cap_u * sizeof(int2));
    unsigned short* w1t = (unsigned short*)alloc(27 * 32 * 32 * 2);
    unsigned short* wdt = (unsigned short*)alloc(8 * 32 * 64 * 2);
    unsigned short* w2t = (unsigned short*)alloc(27 * 64 * 64 * 2);
    unsigned short* w3t = (unsigned short*)alloc(27 * 64 * 32 * 2);
    unsigned short* wupT = (unsigned short*)alloc(8 * 64 * 32 * 2);

    float* st0 = stats + 0 * 128;
    float* st1 = stats + 1 * 128;   // conv1 out (32 ch)
    float* st2 = stats + 2 * 128;   // down out (64 ch)
    float* st3 = stats + 3 * 128;   // conv2 out (64 ch)
    float* st4 = stats + 4 * 128;   // deconv out (32 ch)
    int* cnt_fine   = cnts;               // 26 taps * 32 stride
    int* cnt_coarse = cnts + 26 * 32;     // 26 * 32
    int* cnt_down   = cnts + 52 * 32;     // 8 * 32
    int* cnt_up     = cnts + 60 * 32;     // 8 * 32

    // ---- setup ----
    zero_kernel<<<3, 256, 0, stream>>>(stats, 768);
    zero_kernel<<<16, 256, 0, stream>>>((float*)cnts, 4096);
    zero_kernel<<<ceil_div((long)M * 64, 256), 256, 0, stream>>>(Cf, (long)M * 64);
    wt_transpose<32, 32><<<ceil_div(27 * 32 * 32, 256), 256, 0, stream>>>(w_sub1, w1t, 27);
    wt_transpose<32, 64><<<ceil_div(8 * 32 * 64, 256), 256, 0, stream>>>(w_down, wdt, 8);
    wt_transpose<64, 64><<<ceil_div(27 * 64 * 64, 256), 256, 0, stream>>>(w_sub2, w2t, 27);
    wt_transpose<64, 32><<<ceil_div(27 * 64 * 32, 256), 256, 0, stream>>>(w_sub3, w3t, 27);
    wt_transpose<64, 32><<<ceil_div(8 * 64 * 32, 256), 256, 0, stream>>>(w_up, wupT, 8);
    build_rb_tap<<<dim3(ceil_div(N, 1024), 26), 256, 0, stream>>>(
        nbr_fine, N, N, cap_f, 13, rb_fine, cnt_fine);
    build_rb_tap<<<dim3(ceil_div(M, 1024), 26), 256, 0, stream>>>(
        nbr_coarse, M, M, cap_c, 13, rb_coarse, cnt_coarse);
    build_rb_tap<<<dim3(ceil_div(M, 1024), 8), 256, 0, stream>>>(
        down_idx, M, N, cap_d, 99, rb_down, cnt_down);
    build_rb_up<<<dim3(ceil_div(N, 1024), 8), 256, 0, stream>>>(
        up_cidx, up_k, N, cap_u, rb_up, cnt_up);

    // 1) BN0+ReLU(feat) -> FA [(N+1)x32 bf16]
    bn_stats<32><<<256, 256, 0, stream>>>(feat, N, 32, st0);
    bn_norm_relu_bf16<32, 32><<<ceil_div((long)(N + 1) * 4, 256), 256, 0, stream>>>(
        feat, N, 32, st0, st0, g1, b1, FA);
    // 2) conv1 (27, 32->32): center write + sparse atomics -> D[:,0:32]
    conv_center<32, 32><<<ceil_div(N, 128), 256, 0, stream>>>(
        FA, w1t + 13 * 32 * 32, D, N, N, 64);
    conv_sparse<32, 32, true><<<dim3(ceil_div(cap_f, 128), 26), 256, 0, stream>>>(
        FA, rb_fine, cnt_fine, w1t, D, cap_f, 13, N, 64);
    // 3) BN1+ReLU(skip) -> FB
    bn_stats<32><<<256, 256, 0, stream>>>(D, N, 64, st1);
    bn_norm_relu_bf16<32, 32><<<ceil_div((long)(N + 1) * 4, 256), 256, 0, stream>>>(
        D, N, 64, st1, st1, g2, b2, FB);
    // 4) down conv (8, 32->64): sparse atomics into zeroed Cf
    conv_sparse<32, 64, true><<<dim3(ceil_div(cap_d, 128), 8), 256, 0, stream>>>(
        FB, rb_down, cnt_down, wdt, Cf, cap_d, 99, N, 64);
    // 5) BN2+ReLU(Cf) -> FA [(M+1)x64]
    bn_stats<64><<<256, 256, 0, stream>>>(Cf, M, 64, st2);
    bn_norm_relu_bf16<64, 64><<<ceil_div((long)(M + 1) * 8, 256), 256, 0, stream>>>(
        Cf, M, 64, st2, st2, g3, b3, FA);
    // 6) conv2 (27, 64->64): center write + sparse atomics -> Cf (overwrite)
    conv_center<64, 64><<<ceil_div(M, 128), 256, 0, stream>>>(
        FA, w2t + 13 * 64 * 64, Cf, M, M, 64);
    conv_sparse<64, 64, true><<<dim3(ceil_div(cap_c, 128), 26), 256, 0, stream>>>(
        FA, rb_coarse, cnt_coarse, w2t, Cf, cap_c, 13, M, 64);
    // 7) BN3+ReLU(Cf) -> FB [(M+1)x64]
    bn_stats<64><<<256, 256, 0, stream>>>(Cf, M, 64, st3);
    bn_norm_relu_bf16<64, 64><<<ceil_div((long)(M + 1) * 8, 256), 256, 0, stream>>>(
        Cf, M, 64, st3, st3, g4, b4, FB);
    // 8) deconv (64->32): rulebook segments, direct writes -> D[:,32:64]
    conv_sparse<64, 32, false><<<dim3(ceil_div(cap_u, 128), 8), 256, 0, stream>>>(
        FB, rb_up, cnt_up, wupT, D + 32, cap_u, 99, M, 64);
    // 9) BN4+ReLU(D) -> FA [(N+1)x64]; low 32 ch stats = st1, high 32 = st4
    bn_stats<32><<<256, 256, 0, stream>>>(D + 32, N, 64, st4);
    bn_norm_relu_bf16<64, 32><<<ceil_div((long)(N + 1) * 8, 256), 256, 0, stream>>>(
        D, N, 64, st1, st4, g5, b5, FA);
    // 10) conv3 (27, 64->32): center write + sparse atomics -> d_out
    conv_center<64, 32><<<ceil_div(N, 128), 256, 0, stream>>>(
        FA, w3t + 13 * 64 * 32, (float*)d_out, N, N, 32);
    conv_sparse<64, 32, true><<<dim3(ceil_div(cap_f, 128), 26), 256, 0, stream>>>(
        FA, rb_fine, cnt_fine, w3t, (float*)d_out, cap_f, 13, N, 32);
}

// Round 10
// 681.851 us; speedup vs baseline: 4.8749x; 1.0135x over previous
//
#include <hip/hip_runtime.h>

// ---------------------------------------------------------------------------
// Sparse UNet forward — round 10: rulebook sparse conv.
//   + tap-staggered block mapping (atomic line-collision avoidance)
//   + deconv epilogue BN-stats fusion
//   + merged setup kernels (1 transpose dispatch, 1 zero dispatch)
// ---------------------------------------------------------------------------

#define EPS 1e-4f

typedef __attribute__((ext_vector_type(8))) short short8;   // 8 x bf16
typedef __attribute__((ext_vector_type(4))) float f32x4;

__device__ __forceinline__ unsigned short f2bf(float f) {
    union { float f; unsigned int u; } v; v.f = f;
    unsigned int r = v.u + 0x7fffu + ((v.u >> 16) & 1u);   // RNE
    return (unsigned short)(r >> 16);
}

__global__ void zero_kernel(float* p, long n) {
    long i = (long)blockIdx.x * 256 + threadIdx.x;
    if (i < n) p[i] = 0.f;
}

// Per-channel sum / sumsq -> stats[0:C], stats[C:2C] (atomic accumulate).
template <int C>
__global__ __launch_bounds__(256) void bn_stats(const float* __restrict__ x,
                                                int rows, int stride,
                                                float* __restrict__ stats) {
    const int tid = threadIdx.x;
    const int c = tid & (C - 1);
    const int g = tid / C;
    const int GR = 256 / C;
    float s = 0.f, s2 = 0.f;
    for (int r = blockIdx.x * GR + g; r < rows; r += gridDim.x * GR) {
        float v = x[(size_t)r * stride + c];
        s += v; s2 += v * v;
    }
    __shared__ float sh[2][256];
    sh[0][tid] = s; sh[1][tid] = s2;
    __syncthreads();
    for (int off = 128; off >= C; off >>= 1) {
        if (tid < off) { sh[0][tid] += sh[0][tid + off]; sh[1][tid] += sh[1][tid + off]; }
        __syncthreads();
    }
    if (tid < C) {
        atomicAdd(&stats[c], sh[0][tid]);
        atomicAdd(&stats[C + c], sh[1][tid]);
    }
}

// BN finalize + ReLU -> bf16. Output packed (rows+1) x C, sentinel row zeroed.
template <int C, int CSPLIT>
__global__ __launch_bounds__(256) void bn_norm_relu_bf16(
    const float* __restrict__ x, int rows, int stride,
    const float* __restrict__ stA, const float* __restrict__ stB,
    const float* __restrict__ gamma, const float* __restrict__ beta,
    unsigned short* __restrict__ y) {
    constexpr int TPR = C / 8;
    int gid = blockIdx.x * 256 + threadIdx.x;
    int r = gid / TPR, t = gid % TPR;
    if (r > rows) return;
    short8 o8;
    if (r == rows) {
        for (int j = 0; j < 8; ++j) o8[j] = 0;
    } else {
        const float inv_n = 1.0f / (float)rows;
        const float* xr = x + (size_t)r * stride + t * 8;
        float4 v0 = *(const float4*)(xr);
        float4 v1 = *(const float4*)(xr + 4);
        float vv[8] = {v0.x, v0.y, v0.z, v0.w, v1.x, v1.y, v1.z, v1.w};
#pragma unroll
        for (int j = 0; j < 8; ++j) {
            int c = t * 8 + j;
            const float* st = (c < CSPLIT) ? stA : stB;
            int cc = (c < CSPLIT) ? c : c - CSPLIT;
            int cs = (c < CSPLIT) ? CSPLIT : (C - CSPLIT);
            float mu = st[cc] * inv_n;
            float var = st[cs + cc] * inv_n - mu * mu;
            float sc = gamma[c] * rsqrtf(var + EPS);
            float shf = beta[c] - mu * sc;
            float ov = fmaxf(0.f, fmaf(vv[j], sc, shf));
            o8[j] = (short)f2bf(ov);
        }
    }
    *(short8*)(y + (size_t)r * C + t * 8) = o8;
}

// One dispatch: all 5 weight transposes/casts f32 [K][CIN][COUT] -> bf16
// [K][COUT][CIN].
__device__ __forceinline__ void wt_seg(const float* W, unsigned short* WT,
                                       int id, int CIN, int COUT) {
    int r = id % (CIN * COUT);
    int t = id / (CIN * COUT);
    int co = r / CIN;
    int ci = r % CIN;
    WT[id] = f2bf(W[(size_t)t * CIN * COUT + ci * COUT + co]);
}
__global__ __launch_bounds__(256) void wt_transpose_all(
    const float* w1, const float* wd, const float* w2, const float* w3,
    const float* wu, unsigned short* o1, unsigned short* od,
    unsigned short* o2, unsigned short* o3, unsigned short* ou) {
    int id = blockIdx.x * 256 + threadIdx.x;
    // segment sizes: 27648, 16384, 110592, 55296, 16384 (total 226304)
    if (id < 27648) { wt_seg(w1, o1, id, 32, 32); return; }
    id -= 27648;
    if (id < 16384) { wt_seg(wd, od, id, 32, 64); return; }
    id -= 16384;
    if (id < 110592) { wt_seg(w2, o2, id, 64, 64); return; }
    id -= 110592;
    if (id < 55296) { wt_seg(w3, o3, id, 64, 32); return; }
    id -= 55296;
    if (id < 16384) { wt_seg(wu, ou, id, 64, 32); return; }
}

// ---- rulebook builders (r9, verified fast) ---------------------------------
__global__ __launch_bounds__(256) void build_rb_tap(
    const int* __restrict__ nbr, int rows, int P, int cap, int kskip,
    int2* __restrict__ rb, int* __restrict__ cnt) {
    const int tap = blockIdx.y;
    const int k = tap + (tap >= kskip ? 1 : 0);
    const int* nk = nbr + (size_t)k * rows;
    const int lane = threadIdx.x & 63;
    const int wave = threadIdx.x >> 6;
    const long wbase = (long)blockIdx.x * 1024 + wave * 256;

    unsigned long long masks[4];
    int vs[4], tot[4], wtotal = 0;
#pragma unroll
    for (int c = 0; c < 4; ++c) {
        long m = wbase + c * 64 + lane;
        int v = (m < rows) ? nk[m] : P;
        vs[c] = v;
        masks[c] = __ballot(v != P);
        tot[c] = __popcll(masks[c]);
        wtotal += tot[c];
    }
    __shared__ int sh[5];
    if (lane == 0) sh[wave] = wtotal;
    __syncthreads();
    if (threadIdx.x == 0) {
        int t = sh[0] + sh[1] + sh[2] + sh[3];
        sh[4] = t ? atomicAdd(&cnt[tap * 32], t) : 0;
    }
    __syncthreads();
    int base = sh[4];
    for (int w = 0; w < wave; ++w) base += sh[w];
#pragma unroll
    for (int c = 0; c < 4; ++c) {
        if (vs[c] != P) {
            int rank = __popcll(masks[c] & ((1ull << lane) - 1ull));
            int j = base + rank;
            if (j < cap)
                rb[(size_t)tap * cap + j] = make_int2((int)(wbase + c * 64 + lane), vs[c]);
        }
        base += tot[c];
    }
}

__global__ __launch_bounds__(256) void build_rb_up(
    const int* __restrict__ up_cidx, const int* __restrict__ up_k,
    int rows, int cap, int2* __restrict__ rb, int* __restrict__ cnt) {
    const int s = blockIdx.y;
    const int lane = threadIdx.x & 63;
    const int wave = threadIdx.x >> 6;
    const long wbase = (long)blockIdx.x * 1024 + wave * 256;

    unsigned long long masks[4];
    int cs[4], ok[4], tot[4], wtotal = 0;
#pragma unroll
    for (int c = 0; c < 4; ++c) {
        long i = wbase + c * 64 + lane;
        int seg = (i < rows) ? up_k[i] : -1;
        cs[c] = (i < rows) ? up_cidx[i] : 0;
        ok[c] = (seg == s);
        masks[c] = __ballot(ok[c]);
        tot[c] = __popcll(masks[c]);
        wtotal += tot[c];
    }
    __shared__ int sh[5];
    if (lane == 0) sh[wave] = wtotal;
    __syncthreads();
    if (threadIdx.x == 0) {
        int t = sh[0] + sh[1] + sh[2] + sh[3];
        sh[4] = t ? atomicAdd(&cnt[s * 32], t) : 0;
    }
    __syncthreads();
    int base = sh[4];
    for (int w = 0; w < wave; ++w) base += sh[w];
#pragma unroll
    for (int c = 0; c < 4; ++c) {
        if (ok[c]) {
            int rank = __popcll(masks[c] & ((1ull << lane) - 1ull));
            int j = base + rank;
            if (j < cap)
                rb[(size_t)s * cap + j] = make_int2((int)(wbase + c * 64 + lane), cs[c]);
        }
        base += tot[c];
    }
}

// ---- conv kernels ----------------------------------------------------------

// Dense center-tap GEMM (identity gather): out[m] = fpad[m] @ Wk, plain write.
template <int CIN, int COT>
__global__ __launch_bounds__(256) void conv_center(
    const unsigned short* __restrict__ fpad,
    const unsigned short* __restrict__ Wk,
    float* __restrict__ out, int rows, int P, int out_stride) {
    constexpr int N_SUB = COT / 16;
    constexpr int K_SUB = CIN / 32;
    const int tid = threadIdx.x;
    const int wave = tid >> 6;
    const int lane = tid & 63;
    const int q = lane >> 4;
    const int l15 = lane & 15;
    const int m0 = blockIdx.x * 128 + wave * 32;

    f32x4 acc[2][N_SUB];
#pragma unroll
    for (int mt = 0; mt < 2; ++mt)
#pragma unroll
        for (int nt = 0; nt < N_SUB; ++nt) acc[mt][nt] = (f32x4){0.f, 0.f, 0.f, 0.f};

    short8 a[2][K_SUB], b[N_SUB][K_SUB];
#pragma unroll
    for (int mt = 0; mt < 2; ++mt) {
        int m = m0 + mt * 16 + l15;
        int src = (m < rows) ? m : P;
#pragma unroll
        for (int kf = 0; kf < K_SUB; ++kf)
            a[mt][kf] = *(const short8*)(fpad + (size_t)src * CIN + kf * 32 + q * 8);
    }
#pragma unroll
    for (int nt = 0; nt < N_SUB; ++nt)
#pragma unroll
        for (int kf = 0; kf < K_SUB; ++kf)
            b[nt][kf] = *(const short8*)(Wk + (size_t)(nt * 16 + l15) * CIN + kf * 32 + q * 8);
#pragma unroll
    for (int mt = 0; mt < 2; ++mt)
#pragma unroll
        for (int nt = 0; nt < N_SUB; ++nt)
#pragma unroll
            for (int kf = 0; kf < K_SUB; ++kf)
                acc[mt][nt] = __builtin_amdgcn_mfma_f32_16x16x32_bf16(
                    a[mt][kf], b[nt][kf], acc[mt][nt], 0, 0, 0);
#pragma unroll
    for (int mt = 0; mt < 2; ++mt)
#pragma unroll
        for (int i = 0; i < 4; ++i) {
            int row = m0 + mt * 16 + q * 4 + i;
            if (row < rows) {
#pragma unroll
                for (int nt = 0; nt < N_SUB; ++nt)
                    out[(size_t)row * out_stride + nt * 16 + l15] = acc[mt][nt][i];
            }
        }
}

// Sparse-tap gather-GEMM over compacted rulebook tiles.
//   Tap-staggered block mapping: logical position (x + tap*step) % gridX so
//   concurrent blocks of different taps hit disjoint out-row ranges (atomic
//   line-collision avoidance).
//   stats (non-null, non-atomic path only): fused per-channel sum/sumsq.
template <int CIN, int COT, bool ATOMIC>
__global__ __launch_bounds__(256) void conv_sparse(
    const unsigned short* __restrict__ fpad,
    const int2* __restrict__ rb,
    const int* __restrict__ cnt,
    const unsigned short* __restrict__ WT,
    float* __restrict__ out,
    float* __restrict__ stats,
    int cap, int kskip, int P, int out_stride) {
    constexpr int N_SUB = COT / 16;
    constexpr int K_SUB = CIN / 32;
    const int tap = blockIdx.y;
    int n = cnt[tap * 32];
    n = n < cap ? n : cap;
    const int nbx = gridDim.x;
    const int step = (nbx >> 3) | 1;
    const int px = (int)((blockIdx.x + (unsigned)tap * step) % (unsigned)nbx);
    const int base0 = px * 128;
    if (base0 >= n) return;
    const int k = tap + (tap >= kskip ? 1 : 0);
    const int tid = threadIdx.x;
    const int wave = tid >> 6;
    const int lane = tid & 63;
    const int q = lane >> 4;
    const int l15 = lane & 15;
    const int base = base0 + wave * 32;
    const int2* seg = rb + (size_t)tap * cap;

    f32x4 acc[2][N_SUB];
#pragma unroll
    for (int mt = 0; mt < 2; ++mt)
#pragma unroll
        for (int nt = 0; nt < N_SUB; ++nt) acc[mt][nt] = (f32x4){0.f, 0.f, 0.f, 0.f};

    short8 a[2][K_SUB], b[N_SUB][K_SUB];
#pragma unroll
    for (int mt = 0; mt < 2; ++mt) {
        int j = base + mt * 16 + l15;
        int src = (j < n) ? seg[j].y : P;
#pragma unroll
        for (int kf = 0; kf < K_SUB; ++kf)
            a[mt][kf] = *(const short8*)(fpad + (size_t)src * CIN + kf * 32 + q * 8);
    }
    const unsigned short* Wk = WT + (size_t)k * COT * CIN;
#pragma unroll
    for (int nt = 0; nt < N_SUB; ++nt)
#pragma unroll
        for (int kf = 0; kf < K_SUB; ++kf)
            b[nt][kf] = *(const short8*)(Wk + (size_t)(nt * 16 + l15) * CIN + kf * 32 + q * 8);
#pragma unroll
    for (int mt = 0; mt < 2; ++mt)
#pragma unroll
        for (int nt = 0; nt < N_SUB; ++nt)
#pragma unroll
            for (int kf = 0; kf < K_SUB; ++kf)
                acc[mt][nt] = __builtin_amdgcn_mfma_f32_16x16x32_bf16(
                    a[mt][kf], b[nt][kf], acc[mt][nt], 0, 0, 0);

#pragma unroll
    for (int mt = 0; mt < 2; ++mt)
#pragma unroll
        for (int i = 0; i < 4; ++i) {
            int j = base + mt * 16 + q * 4 + i;
            if (j < n) {
                int row = seg[j].x;
                float* o = out + (size_t)row * out_stride + l15;
#pragma unroll
                for (int nt = 0; nt < N_SUB; ++nt) {
                    if (ATOMIC) atomicAdd(o + nt * 16, acc[mt][nt][i]);
                    else        o[nt * 16] = acc[mt][nt][i];
                }
            }
        }

    // Fused BN stats (final-value writes only): OOB lanes hold acc==0.
    if (!ATOMIC && stats) {
        __shared__ float ssum[COT], ssq[COT];
        for (int i = tid; i < 2 * COT; i += 256)
            (i < COT ? ssum[i] : ssq[i - COT]) = 0.f;
        __syncthreads();
#pragma unroll
        for (int nt = 0; nt < N_SUB; ++nt) {
            float s = 0.f, s2 = 0.f;
#pragma unroll
            for (int mt = 0; mt < 2; ++mt)
#pragma unroll
                for (int i = 0; i < 4; ++i) {
                    float v = acc[mt][nt][i];
                    s += v; s2 += v * v;
                }
            s += __shfl_xor(s, 16);  s += __shfl_xor(s, 32);
            s2 += __shfl_xor(s2, 16); s2 += __shfl_xor(s2, 32);
            if (q == 0) {
                atomicAdd(&ssum[nt * 16 + l15], s);
                atomicAdd(&ssq[nt * 16 + l15], s2);
            }
        }
        __syncthreads();
        if (tid < COT) {
            atomicAdd(&stats[tid], ssum[tid]);
            atomicAdd(&stats[COT + tid], ssq[tid]);
        }
    }
}

static inline int ceil_div(long a, long b) { return (int)((a + b - 1) / b); }

extern "C" void kernel_launch(void* const* d_in, const int* in_sizes, int n_in,
                              void* d_out, int out_size, void* d_ws, size_t ws_size,
                              hipStream_t stream) {
    const float* feat   = (const float*)d_in[0];
    const float* w_sub1 = (const float*)d_in[1];
    const float* w_down = (const float*)d_in[2];
    const float* w_sub2 = (const float*)d_in[3];
    const float* w_up   = (const float*)d_in[4];
    const float* w_sub3 = (const float*)d_in[5];
    const float* g1 = (const float*)d_in[6],  *b1 = (const float*)d_in[7];
    const float* g2 = (const float*)d_in[8],  *b2 = (const float*)d_in[9];
    const float* g3 = (const float*)d_in[10], *b3 = (const float*)d_in[11];
    const float* g4 = (const float*)d_in[12], *b4 = (const float*)d_in[13];
    const float* g5 = (const float*)d_in[14], *b5 = (const float*)d_in[15];
    const int* nbr_fine   = (const int*)d_in[16];
    const int* nbr_coarse = (const int*)d_in[17];
    const int* down_idx   = (const int*)d_in[18];
    const int* up_cidx    = (const int*)d_in[19];
    const int* up_k       = (const int*)d_in[20];

    const int N = in_sizes[0] / 32;
    const int M = in_sizes[17] / 27;
    const size_t maxr = (size_t)((N > M ? N : M) + 1);

    // rulebook caps (expected max: fine ~2.6k/tap; coarse ~18k; down/up ~25.6k)
    const int cap_f = 8192;
    const int cap_c = 49152;
    const int cap_d = 32768;
    const int cap_u = 32768;

    char* ws = (char*)d_ws;
    size_t off = 0;
    auto alloc = [&](size_t bytes) { void* p = ws + off; off += (bytes + 255) & ~(size_t)255; return p; };
    float* stats = (float*)alloc(768 * sizeof(float));
    int*   cnts  = (int*)alloc(4096 * sizeof(int));   // padded: 32 ints/tap
    float* D  = (float*)alloc((size_t)N * 64 * sizeof(float));        // concat buf [skip|up]
    float* Cf = (float*)alloc((size_t)M * 64 * sizeof(float));        // coarse f32 temp
    unsigned short* FA = (unsigned short*)alloc(maxr * 64 * 2);
    unsigned short* FB = (unsigned short*)alloc(maxr * 64 * 2);
    int2* rb_fine   = (int2*)alloc((size_t)26 * cap_f * sizeof(int2));
    int2* rb_coarse = (int2*)alloc((size_t)26 * cap_c * sizeof(int2));
    int2* rb_down   = (int2*)alloc((size_t)8 * cap_d * sizeof(int2));
    int2* rb_up     = (int2*)alloc((size_t)8 * cap_u * sizeof(int2));
    unsigned short* w1t = (unsigned short*)alloc(27 * 32 * 32 * 2);
    unsigned short* wdt = (unsigned short*)alloc(8 * 32 * 64 * 2);
    unsigned short* w2t = (unsigned short*)alloc(27 * 64 * 64 * 2);
    unsigned short* w3t = (unsigned short*)alloc(27 * 64 * 32 * 2);
    unsigned short* wupT = (unsigned short*)alloc(8 * 64 * 32 * 2);

    float* st0 = stats + 0 * 128;
    float* st1 = stats + 1 * 128;   // conv1 out (32 ch)
    float* st2 = stats + 2 * 128;   // down out (64 ch)
    float* st3 = stats + 3 * 128;   // conv2 out (64 ch)
    float* st4 = stats + 4 * 128;   // deconv out (32 ch, fused in deconv)
    int* cnt_fine   = cnts;               // 26 taps * 32 stride
    int* cnt_coarse = cnts + 26 * 32;
    int* cnt_down   = cnts + 52 * 32;
    int* cnt_up     = cnts + 60 * 32;

    // ---- setup ----
    zero_kernel<<<19, 256, 0, stream>>>(stats, 768 + 4096);  // stats + cnts (contiguous)
    zero_kernel<<<ceil_div((long)M * 64, 256), 256, 0, stream>>>(Cf, (long)M * 64);
    wt_transpose_all<<<ceil_div(226304, 256), 256, 0, stream>>>(
        w_sub1, w_down, w_sub2, w_sub3, w_up, w1t, wdt, w2t, w3t, wupT);
    build_rb_tap<<<dim3(ceil_div(N, 1024), 26), 256, 0, stream>>>(
        nbr_fine, N, N, cap_f, 13, rb_fine, cnt_fine);
    build_rb_tap<<<dim3(ceil_div(M, 1024), 26), 256, 0, stream>>>(
        nbr_coarse, M, M, cap_c, 13, rb_coarse, cnt_coarse);
    build_rb_tap<<<dim3(ceil_div(M, 1024), 8), 256, 0, stream>>>(
        down_idx, M, N, cap_d, 99, rb_down, cnt_down);
    build_rb_up<<<dim3(ceil_div(N, 1024), 8), 256, 0, stream>>>(
        up_cidx, up_k, N, cap_u, rb_up, cnt_up);

    // 1) BN0+ReLU(feat) -> FA [(N+1)x32 bf16]
    bn_stats<32><<<256, 256, 0, stream>>>(feat, N, 32, st0);
    bn_norm_relu_bf16<32, 32><<<ceil_div((long)(N + 1) * 4, 256), 256, 0, stream>>>(
        feat, N, 32, st0, st0, g1, b1, FA);
    // 2) conv1 (27, 32->32): center write + sparse atomics -> D[:,0:32]
    conv_center<32, 32><<<ceil_div(N, 128), 256, 0, stream>>>(
        FA, w1t + 13 * 32 * 32, D, N, N, 64);
    conv_sparse<32, 32, true><<<dim3(cap_f / 128, 26), 256, 0, stream>>>(
        FA, rb_fine, cnt_fine, w1t, D, nullptr, cap_f, 13, N, 64);
    // 3) BN1+ReLU(skip) -> FB
    bn_stats<32><<<256, 256, 0, stream>>>(D, N, 64, st1);
    bn_norm_relu_bf16<32, 32><<<ceil_div((long)(N + 1) * 4, 256), 256, 0, stream>>>(
        D, N, 64, st1, st1, g2, b2, FB);
    // 4) down conv (8, 32->64): sparse atomics into zeroed Cf
    conv_sparse<32, 64, true><<<dim3(cap_d / 128, 8), 256, 0, stream>>>(
        FB, rb_down, cnt_down, wdt, Cf, nullptr, cap_d, 99, N, 64);
    // 5) BN2+ReLU(Cf) -> FA [(M+1)x64]
    bn_stats<64><<<256, 256, 0, stream>>>(Cf, M, 64, st2);
    bn_norm_relu_bf16<64, 64><<<ceil_div((long)(M + 1) * 8, 256), 256, 0, stream>>>(
        Cf, M, 64, st2, st2, g3, b3, FA);
    // 6) conv2 (27, 64->64): center write + sparse atomics -> Cf (overwrite)
    conv_center<64, 64><<<ceil_div(M, 128), 256, 0, stream>>>(
        FA, w2t + 13 * 64 * 64, Cf, M, M, 64);
    conv_sparse<64, 64, true><<<dim3(cap_c / 128, 26), 256, 0, stream>>>(
        FA, rb_coarse, cnt_coarse, w2t, Cf, nullptr, cap_c, 13, M, 64);
    // 7) BN3+ReLU(Cf) -> FB [(M+1)x64]
    bn_stats<64><<<256, 256, 0, stream>>>(Cf, M, 64, st3);
    bn_norm_relu_bf16<64, 64><<<ceil_div((long)(M + 1) * 8, 256), 256, 0, stream>>>(
        Cf, M, 64, st3, st3, g4, b4, FB);
    // 8) deconv (64->32): segments, direct writes -> D[:,32:64]; fused stats st4
    conv_sparse<64, 32, false><<<dim3(cap_u / 128, 8), 256, 0, stream>>>(
        FB, rb_up, cnt_up, wupT, D + 32, st4, cap_u, 99, M, 64);
    // 9) BN4+ReLU(D) -> FA [(N+1)x64]; low 32 ch stats = st1, high 32 = st4
    bn_norm_relu_bf16<64, 32><<<ceil_div((long)(N + 1) * 8, 256), 256, 0, stream>>>(
        D, N, 64, st1, st4, g5, b5, FA);
    // 10) conv3 (27, 64->32): center write + sparse atomics -> d_out
    conv_center<64, 32><<<ceil_div(N, 128), 256, 0, stream>>>(
        FA, w3t + 13 * 64 * 32, (float*)d_out, N, N, 32);
    conv_sparse<64, 32, true><<<dim3(cap_f / 128, 26), 256, 0, stream>>>(
        FA, rb_fine, cnt_fine, w3t, (float*)d_out, nullptr, cap_f, 13, N, 32);
}